// Round 1
// baseline (7325.921 us; speedup 1.0000x reference)
//
#include <hip/hip_runtime.h>
#include <math.h>

#define BB 32
#define CC 256
#define LL 4096

// ---------- bf16 helpers (RTN pack, cheap unpack) ----------
__device__ __forceinline__ unsigned short f2bf(float f) {
  unsigned u = __float_as_uint(f);
  u = (u + 0x7FFFu + ((u >> 16) & 1u)) >> 16;
  return (unsigned short)u;
}
__device__ __forceinline__ float bf2f_lo(unsigned v) { return __uint_as_float(v << 16); }
__device__ __forceinline__ float bf2f_hi(unsigned v) { return __uint_as_float(v & 0xFFFF0000u); }

// ---------------- init kernels ----------------
// Fold eval-mode BN into conv weights + bias: bn(conv(x)) = conv(x)*s + (b - m*s), s = g/sqrt(v+eps)
__global__ void init_fold(const float* __restrict__ w1, const float* __restrict__ g1,
                          const float* __restrict__ b1, const float* __restrict__ m1,
                          const float* __restrict__ v1,
                          const float* __restrict__ w2, const float* __restrict__ g2,
                          const float* __restrict__ b2, const float* __restrict__ m2,
                          const float* __restrict__ v2,
                          float* __restrict__ w1f, float* __restrict__ b1f,
                          float* __restrict__ w2f, float* __restrict__ b2f) {
  int id = blockIdx.x * 256 + threadIdx.x;
  if (id >= CC * CC * 3) return;
  int co = id / (CC * 3);
  float s1 = g1[co] / sqrtf(v1[co] + 1e-5f);
  float s2 = g2[co] / sqrtf(v2[co] + 1e-5f);
  w1f[id] = w1[id] * s1;
  w2f[id] = w2[id] * s2;
  if (id < CC) {
    float ss1 = g1[id] / sqrtf(v1[id] + 1e-5f);
    float ss2 = g2[id] / sqrtf(v2[id] + 1e-5f);
    b1f[id] = b1[id] - m1[id] * ss1;
    b2f[id] = b2[id] - m2[id] * ss2;
  }
}

// DmT[n][k] = Dm[k][n] = 2*cos(pi*k*(2n+1)/512)  (scipy DCT-II, norm=None)
__global__ void init_dct(float* __restrict__ DmT) {
  int id = blockIdx.x * 256 + threadIdx.x; // 65536
  int n = id >> 8, k = id & 255;
  double v = 2.0 * cos(3.14159265358979323846 * (double)k * (2.0 * n + 1.0) / 512.0);
  DmT[id] = (float)v;
}

// fc1T[c][j] = fc1_w[j][c]  (256x512); fc2T[j][c] = fc2_w[c][j]  (512x256)
__global__ void init_tr(const float* __restrict__ fc1, const float* __restrict__ fc2,
                        float* __restrict__ fc1T, float* __restrict__ fc2T) {
  int id = blockIdx.x * 256 + threadIdx.x; // 262144
  if (id < 131072) {
    int c = id >> 9, j = id & 511;
    fc1T[id] = fc1[j * 256 + c];
  } else {
    int id2 = id - 131072;
    int j = id2 >> 8, c = id2 & 255;
    fc2T[id2] = fc2[c * 512 + j];
  }
}

// ---------------- conv (+folded BN) ----------------
// tile: 32 co x 128 l, one b. thread = 4 co x 4 l (l strided by 32 -> conflict-free LDS reads).
// TRANS: write xp[(b*L+l)*256 + co] via LDS transpose (coalesced 128B segments).
template <bool RELU, bool TRANS>
__global__ __launch_bounds__(256) void conv_bn_kernel(
    const float* __restrict__ in, const float* __restrict__ wf,
    const float* __restrict__ bf, float* __restrict__ outp) {
  __shared__ float xs[32][132];      // [ci][l0-1 .. l0+128] (130 used)
  __shared__ float wsm[32][32][3];   // [ci][co][t]
  const int tid = threadIdx.x;
  const int tx = tid & 31;           // l lane
  const int ty = tid >> 5;           // co group (co = co0 + ty*4 + u)
  const int l0 = blockIdx.x << 7;
  const int co0 = blockIdx.y << 5;
  const int b = blockIdx.z;

  float acc[4][4] = {};
  for (int cb = 0; cb < 8; ++cb) {
    const int ci0 = cb << 5;
    for (int idx = tid; idx < 32 * 130; idx += 256) {
      int i = idx / 130, p = idx - 130 * i;
      int gl = l0 - 1 + p;
      float v = 0.f;
      if (gl >= 0 && gl < LL) v = in[((b << 8) + ci0 + i) * LL + gl];
      xs[i][p] = v;
    }
    for (int idx = tid; idx < 32 * 32 * 3; idx += 256) {
      int co_l = idx / 96; int rem = idx - 96 * co_l; int i = rem / 3; int t = rem - 3 * i;
      wsm[i][co_l][t] = wf[(co0 + co_l) * 768 + (ci0 + i) * 3 + t];
    }
    __syncthreads();
    for (int i = 0; i < 32; ++i) {
      float w[4][3];
#pragma unroll
      for (int u = 0; u < 4; ++u)
#pragma unroll
        for (int t = 0; t < 3; ++t) w[u][t] = wsm[i][ty * 4 + u][t];
#pragma unroll
      for (int j = 0; j < 4; ++j) {
        const int base = tx + 32 * j;   // xs index of x[l-1]
        float x0 = xs[i][base], x1 = xs[i][base + 1], x2 = xs[i][base + 2];
#pragma unroll
        for (int u = 0; u < 4; ++u)
          acc[u][j] += w[u][0] * x0 + w[u][1] * x1 + w[u][2] * x2;
      }
    }
    __syncthreads();
  }
  if (!TRANS) {
#pragma unroll
    for (int u = 0; u < 4; ++u) {
      const int co = co0 + ty * 4 + u;
      const float bias = bf[co];
#pragma unroll
      for (int j = 0; j < 4; ++j) {
        float v = acc[u][j] + bias;
        if (RELU) v = fmaxf(v, 0.f);
        outp[((b << 8) + co) * LL + l0 + tx + 32 * j] = v;
      }
    }
  } else {
#pragma unroll
    for (int u = 0; u < 4; ++u) {
      const int co = ty * 4 + u;
      const float bias = bf[co0 + co];
#pragma unroll
      for (int j = 0; j < 4; ++j) {
        float v = acc[u][j] + bias;
        if (RELU) v = fmaxf(v, 0.f);
        xs[co][tx + 32 * j] = v;   // reuse xs as transpose scratch (safe: loop ended with sync)
      }
    }
    __syncthreads();
    for (int idx = tid; idx < 4096; idx += 256) {
      int l_i = idx >> 5, co_i = idx & 31;
      outp[((b << 12) + l0 + l_i) * 256 + co0 + co_i] = xs[co_i][l_i];
    }
  }
}

// ---------------- fused FECAM ----------------
// block = 16 rows (one (b,l) per row). wave tr owns rows 4tr..4tr+3; lane tc owns cols 4tc..4tc+3.
// DCT -> LN -> fc1+relu -> fc2 -> sigmoid -> LN -> *xp -> +x -> relu, all in-block.
__global__ __launch_bounds__(256) void fecam_kernel(
    const float* __restrict__ xp, const float* __restrict__ xin,
    const float* __restrict__ DmT, const float* __restrict__ fc1T,
    const float* __restrict__ fc2T, const float* __restrict__ lng,
    const float* __restrict__ lnb, float* __restrict__ outp) {
  __shared__ float xsT[256][20];          // xp rows, transposed [c][r]
  __shared__ float Bs[16][260];           // weight chunk [n][k]
  __shared__ unsigned short sdT[256][20]; // bf16 sd, reused for fw
  __shared__ unsigned short hT[512][20];  // bf16 h

  const int tid = threadIdx.x;
  const int tr = tid >> 6;
  const int tc = tid & 63;
  const int row0 = blockIdx.x << 4;
  const int b = row0 >> 12;
  const int l0 = row0 & 4095;

  for (int idx = tid; idx < 4096; idx += 256) {
    int r = idx >> 8, c = idx & 255;
    xsT[c][r] = xp[(row0 + r) * 256 + c];
  }

  float4 g4 = *(const float4*)&lng[4 * tc];
  float4 bl4 = *(const float4*)&lnb[4 * tc];
  const float gj[4] = {g4.x, g4.y, g4.z, g4.w};
  const float bj[4] = {bl4.x, bl4.y, bl4.z, bl4.w};

  // ---------- DCT: freq = xp @ DmT ----------
  float acc[4][4] = {};
  for (int nc = 0; nc < 16; ++nc) {
    for (int idx = tid; idx < 4096; idx += 256) {
      int n = idx >> 8, k = idx & 255;
      Bs[n][k] = DmT[(nc * 16 + n) * 256 + k];
    }
    __syncthreads();
#pragma unroll 4
    for (int n = 0; n < 16; ++n) {
      const int nn = nc * 16 + n;
      float4 av = *(const float4*)&xsT[nn][4 * tr];   // wave-broadcast b128
      float4 bv = *(const float4*)&Bs[n][4 * tc];     // contiguous b128
      const float aa[4] = {av.x, av.y, av.z, av.w};
      const float bb[4] = {bv.x, bv.y, bv.z, bv.w};
#pragma unroll
      for (int i = 0; i < 4; ++i)
#pragma unroll
        for (int j = 0; j < 4; ++j) acc[i][j] = fmaf(aa[i], bb[j], acc[i][j]);
    }
    __syncthreads();
  }

  // ---------- LN(freq) -> sd (bf16) ----------
#pragma unroll
  for (int i = 0; i < 4; ++i) {
    float s1 = acc[i][0] + acc[i][1] + acc[i][2] + acc[i][3];
    float s2 = acc[i][0] * acc[i][0] + acc[i][1] * acc[i][1] +
               acc[i][2] * acc[i][2] + acc[i][3] * acc[i][3];
#pragma unroll
    for (int m = 1; m < 64; m <<= 1) {
      s1 += __shfl_xor(s1, m, 64);
      s2 += __shfl_xor(s2, m, 64);
    }
    float mu = s1 * (1.f / 256.f);
    float var = s2 * (1.f / 256.f) - mu * mu;
    float inv = 1.f / sqrtf(var + 1e-6f);
#pragma unroll
    for (int j = 0; j < 4; ++j) {
      float v = (acc[i][j] - mu) * inv * gj[j] + bj[j];
      sdT[4 * tc + j][4 * tr + i] = f2bf(v);
    }
  }

  // ---------- fc1 + relu -> h (bf16) ----------
  for (int half = 0; half < 2; ++half) {
    float hacc[4][4] = {};
    for (int nc = 0; nc < 16; ++nc) {
      for (int idx = tid; idx < 4096; idx += 256) {
        int n = idx >> 8, k = idx & 255;
        Bs[n][k] = fc1T[(nc * 16 + n) * 512 + half * 256 + k];
      }
      __syncthreads();
#pragma unroll 4
      for (int n = 0; n < 16; ++n) {
        const int nn = nc * 16 + n;
        uint2 ap = *(const uint2*)&sdT[nn][4 * tr];
        const float aa[4] = {bf2f_lo(ap.x), bf2f_hi(ap.x), bf2f_lo(ap.y), bf2f_hi(ap.y)};
        float4 bv = *(const float4*)&Bs[n][4 * tc];
        const float bb[4] = {bv.x, bv.y, bv.z, bv.w};
#pragma unroll
        for (int i = 0; i < 4; ++i)
#pragma unroll
          for (int j = 0; j < 4; ++j) hacc[i][j] = fmaf(aa[i], bb[j], hacc[i][j]);
      }
      __syncthreads();
    }
#pragma unroll
    for (int i = 0; i < 4; ++i)
#pragma unroll
      for (int j = 0; j < 4; ++j)
        hT[half * 256 + 4 * tc + j][4 * tr + i] = f2bf(fmaxf(hacc[i][j], 0.f));
  }

  // ---------- fc2 ----------
  float facc[4][4] = {};
  for (int nc = 0; nc < 32; ++nc) {
    for (int idx = tid; idx < 4096; idx += 256) {
      int n = idx >> 8, k = idx & 255;
      Bs[n][k] = fc2T[(nc * 16 + n) * 256 + k];
    }
    __syncthreads();
#pragma unroll 4
    for (int n = 0; n < 16; ++n) {
      const int nn = nc * 16 + n;
      uint2 ap = *(const uint2*)&hT[nn][4 * tr];
      const float aa[4] = {bf2f_lo(ap.x), bf2f_hi(ap.x), bf2f_lo(ap.y), bf2f_hi(ap.y)};
      float4 bv = *(const float4*)&Bs[n][4 * tc];
      const float bb[4] = {bv.x, bv.y, bv.z, bv.w};
#pragma unroll
      for (int i = 0; i < 4; ++i)
#pragma unroll
        for (int j = 0; j < 4; ++j) facc[i][j] = fmaf(aa[i], bb[j], facc[i][j]);
    }
    __syncthreads();
  }

  // ---------- sigmoid + LN -> fw (bf16, reuse sdT) ----------
#pragma unroll
  for (int i = 0; i < 4; ++i) {
    float sv[4];
#pragma unroll
    for (int j = 0; j < 4; ++j) sv[j] = 1.f / (1.f + expf(-facc[i][j]));
    float s1 = sv[0] + sv[1] + sv[2] + sv[3];
    float s2 = sv[0] * sv[0] + sv[1] * sv[1] + sv[2] * sv[2] + sv[3] * sv[3];
#pragma unroll
    for (int m = 1; m < 64; m <<= 1) {
      s1 += __shfl_xor(s1, m, 64);
      s2 += __shfl_xor(s2, m, 64);
    }
    float mu = s1 * (1.f / 256.f);
    float var = s2 * (1.f / 256.f) - mu * mu;
    float inv = 1.f / sqrtf(var + 1e-6f);
#pragma unroll
    for (int j = 0; j < 4; ++j) {
      float fw = (sv[j] - mu) * inv * gj[j] + bj[j];
      sdT[4 * tc + j][4 * tr + i] = f2bf(fw);
    }
  }
  __syncthreads();

  // ---------- out[b][c][l] = relu(xp*fw + x), coalesced along l ----------
  const int li = tid & 15, cg = tid >> 4;
#pragma unroll
  for (int cc = 0; cc < 16; ++cc) {
    int c = cg * 16 + cc;
    float fw = bf2f_lo((unsigned)sdT[c][li]);
    float xv = xsT[c][li];
    int ofs = ((b << 8) + c) * LL + l0 + li;
    float o = fmaf(xv, fw, xin[ofs]);
    outp[ofs] = fmaxf(o, 0.f);
  }
}

extern "C" void kernel_launch(void* const* d_in, const int* in_sizes, int n_in,
                              void* d_out, int out_size, void* d_ws, size_t ws_size,
                              hipStream_t stream) {
  const float* x    = (const float*)d_in[0];
  const float* w1   = (const float*)d_in[1];
  const float* g1   = (const float*)d_in[2];
  const float* b1   = (const float*)d_in[3];
  const float* m1   = (const float*)d_in[4];
  const float* v1   = (const float*)d_in[5];
  const float* w2   = (const float*)d_in[6];
  const float* g2   = (const float*)d_in[7];
  const float* b2   = (const float*)d_in[8];
  const float* m2   = (const float*)d_in[9];
  const float* v2   = (const float*)d_in[10];
  const float* fc1  = (const float*)d_in[11];
  const float* fc2  = (const float*)d_in[12];
  const float* lng  = (const float*)d_in[13];
  const float* lnb  = (const float*)d_in[14];
  float* out = (float*)d_out;

  float* ws   = (float*)d_ws;
  float* w1f  = ws;                  // 196608
  float* w2f  = ws + 196608;         // 196608
  float* b1f  = ws + 393216;         // 256
  float* b2f  = ws + 393472;         // 256
  float* DmT  = ws + 393728;         // 65536
  float* fc1T = ws + 459264;         // 131072
  float* fc2T = ws + 590336;         // 131072
  float* out1 = ws + 721408;         // 33554432 (conv1 out, [B][C][L])
  float* xpb  = ws + 34275840;       // 33554432 (conv2 out, [B*L][C])
  // total 67830272 floats = 271.3 MB of d_ws

  init_fold<<<768, 256, 0, stream>>>(w1, g1, b1, m1, v1, w2, g2, b2, m2, v2,
                                     w1f, b1f, w2f, b2f);
  init_dct<<<256, 256, 0, stream>>>(DmT);
  init_tr<<<1024, 256, 0, stream>>>(fc1, fc2, fc1T, fc2T);

  dim3 cgrid(LL / 128, CC / 32, BB);
  conv_bn_kernel<true, false><<<cgrid, 256, 0, stream>>>(x, w1f, b1f, out1);
  conv_bn_kernel<false, true><<<cgrid, 256, 0, stream>>>(out1, w2f, b2f, xpb);

  fecam_kernel<<<BB * LL / 16, 256, 0, stream>>>(xpb, x, DmT, fc1T, fc2T, lng, lnb, out);
}

// Round 2
// 2558.746 us; speedup vs baseline: 2.8631x; 2.8631x over previous
//
#include <hip/hip_runtime.h>
#include <math.h>

#define BB 32
#define CC 256
#define LL 4096

typedef __attribute__((ext_vector_type(8))) short bf16x8;
typedef __attribute__((ext_vector_type(4))) float f32x4;

__device__ __forceinline__ unsigned short f2bf(float f) {
  unsigned u = __float_as_uint(f);
  u = (u + 0x7FFFu + ((u >> 16) & 1u)) >> 16;
  return (unsigned short)u;
}
__device__ __forceinline__ float bf2f(unsigned short v) {
  return __uint_as_float(((unsigned)v) << 16);
}

// ---------------- init: fold BN into conv weights ----------------
__global__ void init_fold(const float* __restrict__ w1, const float* __restrict__ g1,
                          const float* __restrict__ b1, const float* __restrict__ m1,
                          const float* __restrict__ v1,
                          const float* __restrict__ w2, const float* __restrict__ g2,
                          const float* __restrict__ b2, const float* __restrict__ m2,
                          const float* __restrict__ v2,
                          float* __restrict__ w1f, float* __restrict__ b1f,
                          float* __restrict__ w2f, float* __restrict__ b2f) {
  int id = blockIdx.x * 256 + threadIdx.x;
  if (id >= CC * CC * 3) return;
  int co = id / (CC * 3);
  float s1 = g1[co] / sqrtf(v1[co] + 1e-5f);
  float s2 = g2[co] / sqrtf(v2[co] + 1e-5f);
  w1f[id] = w1[id] * s1;
  w2f[id] = w2[id] * s2;
  if (id < CC) {
    float ss1 = g1[id] / sqrtf(v1[id] + 1e-5f);
    float ss2 = g2[id] / sqrtf(v2[id] + 1e-5f);
    b1f[id] = b1[id] - m1[id] * ss1;
    b2f[id] = b2[id] - m2[id] * ss2;
  }
}

// ---------------- init: B matrices in fragment-linear bf16 order ----------------
// Layout: [kc][nt][lane(64)][j(8)]; element = W[n = nt*16 + (lane&15)][k = kc*32 + (lane>>4)*8 + j]
// Dm[n][k] = 2*cos(pi*n*(2k+1)/512) (DCT-II);  fc1_w is [512][256]=[n][k];  fc2_w is [256][512]=[n][k]
__global__ void init_bsw(const float* __restrict__ fc1, const float* __restrict__ fc2,
                         unsigned short* __restrict__ Bd, unsigned short* __restrict__ B1,
                         unsigned short* __restrict__ B2) {
  int id = blockIdx.x * 256 + threadIdx.x; // 327680 total
  if (id < 65536) {
    int i = id;
    int kc = i >> 13, nt = (i >> 9) & 15, L = (i >> 3) & 63, j = i & 7;
    int n = nt * 16 + (L & 15), k = kc * 32 + (L >> 4) * 8 + j;
    double v = 2.0 * cos(3.14159265358979323846 * (double)n * (2.0 * k + 1.0) / 512.0);
    Bd[i] = f2bf((float)v);
  } else if (id < 65536 + 131072) {
    int i = id - 65536;
    int kc = i >> 14, nt = (i >> 9) & 31, L = (i >> 3) & 63, j = i & 7;
    int n = nt * 16 + (L & 15), k = kc * 32 + (L >> 4) * 8 + j;
    B1[i] = f2bf(fc1[n * 256 + k]);
  } else {
    int i = id - 65536 - 131072;
    int kc = i >> 13, nt = (i >> 9) & 15, L = (i >> 3) & 63, j = i & 7;
    int n = nt * 16 + (L & 15), k = kc * 32 + (L >> 4) * 8 + j;
    B2[i] = f2bf(fc2[n * 512 + k]);
  }
}

// ---------------- conv (+folded BN) ----------------
// TRANS=false: natural fp32 [b][co][l] output (conv1).
// TRANS=true : bf16 A-fragment-linear output for the DCT GEMM (conv2):
//   xp_sw[((MT*8 + kc)*64 + lane)*8 + j], MT=row/16 (row=b*4096+l), kc=co/32,
//   lane=((co&31)>>3)*16 + (l&15), j=co&7
template <bool RELU, bool TRANS>
__global__ __launch_bounds__(256) void conv_bn_kernel(
    const float* __restrict__ in, const float* __restrict__ wf,
    const float* __restrict__ bf, float* __restrict__ outp,
    unsigned short* __restrict__ outsw) {
  __shared__ float xs[32][132];
  __shared__ float wsm[32][32][3];
  const int tid = threadIdx.x;
  const int tx = tid & 31;
  const int ty = tid >> 5;
  const int l0 = blockIdx.x << 7;
  const int co0 = blockIdx.y << 5;
  const int b = blockIdx.z;

  float acc[4][4] = {};
  for (int cb = 0; cb < 8; ++cb) {
    const int ci0 = cb << 5;
    for (int idx = tid; idx < 32 * 130; idx += 256) {
      int i = idx / 130, p = idx - 130 * i;
      int gl = l0 - 1 + p;
      float v = 0.f;
      if (gl >= 0 && gl < LL) v = in[((b << 8) + ci0 + i) * LL + gl];
      xs[i][p] = v;
    }
    for (int idx = tid; idx < 32 * 32 * 3; idx += 256) {
      int co_l = idx / 96; int rem = idx - 96 * co_l; int i = rem / 3; int t = rem - 3 * i;
      wsm[i][co_l][t] = wf[(co0 + co_l) * 768 + (ci0 + i) * 3 + t];
    }
    __syncthreads();
    for (int i = 0; i < 32; ++i) {
      float w[4][3];
#pragma unroll
      for (int u = 0; u < 4; ++u)
#pragma unroll
        for (int t = 0; t < 3; ++t) w[u][t] = wsm[i][ty * 4 + u][t];
#pragma unroll
      for (int j = 0; j < 4; ++j) {
        const int base = tx + 32 * j;
        float x0 = xs[i][base], x1 = xs[i][base + 1], x2 = xs[i][base + 2];
#pragma unroll
        for (int u = 0; u < 4; ++u)
          acc[u][j] += w[u][0] * x0 + w[u][1] * x1 + w[u][2] * x2;
      }
    }
    __syncthreads();
  }
  if (!TRANS) {
#pragma unroll
    for (int u = 0; u < 4; ++u) {
      const int co = co0 + ty * 4 + u;
      const float bias = bf[co];
#pragma unroll
      for (int j = 0; j < 4; ++j) {
        float v = acc[u][j] + bias;
        if (RELU) v = fmaxf(v, 0.f);
        outp[((b << 8) + co) * LL + l0 + tx + 32 * j] = v;
      }
    }
  } else {
#pragma unroll
    for (int u = 0; u < 4; ++u) {
      const int co = ty * 4 + u;
      const float bias = bf[co0 + co];
#pragma unroll
      for (int j = 0; j < 4; ++j) {
        float v = acc[u][j] + bias;
        if (RELU) v = fmaxf(v, 0.f);
        xs[co][tx + 32 * j] = v;
      }
    }
    __syncthreads();
    const int MT0 = ((b << 12) + l0) >> 4;
    const int kc = blockIdx.y;
    const int ch = tid >> 5;
#pragma unroll
    for (int s = 0; s < 2; ++s) {
      int L = ((tid & 31) << 1) | s;
      int g = L >> 4, cf = L & 15;
      alignas(16) unsigned short tmp[8];
#pragma unroll
      for (int j = 0; j < 8; ++j)
        tmp[j] = f2bf(xs[g * 8 + j][ch * 16 + cf]);
      *(uint4*)&outsw[(((size_t)(MT0 + ch) * 8 + kc) << 9) + L * 8] = *(const uint4*)tmp;
    }
  }
}

// ---------------- fused GEMM chain (MFMA 16x16x32 bf16) ----------------
// Block: 64 rows (4 m-tiles) x 256 cols (16 n-tiles), 4 waves; wave w owns cols [64w,64w+64).
// STAGE 0: freq = xp @ Dm^T, LN -> sd (A-frag order)
// STAGE 1: h = relu(sd @ fc1^T) -> h (A-frag order); grid.y picks n-half
// STAGE 2: fw = LN(sigmoid(h @ fc2^T)); out = relu(xp*fw + x)
template <int STAGE>
__global__ __launch_bounds__(256, 3) void gemm_stage(
    const unsigned short* __restrict__ Ag, const unsigned short* __restrict__ Bg,
    const float* __restrict__ lng, const float* __restrict__ lnb,
    unsigned short* __restrict__ Og,
    const unsigned short* __restrict__ xpsw, const float* __restrict__ xin,
    float* __restrict__ outp) {
  __shared__ char smem[53248];
  unsigned short* smemB = (unsigned short*)smem;            // 16 KB B chunk
  unsigned short* swz = (unsigned short*)(smem + 16384);    // stage0/1: [64][264]; stage2: fwT [256][68]
  float* ps1 = (float*)(smem + 51200);                      // [4][64]
  float* ps2 = (float*)(smem + 51200 + 1024);               // [4][64]

  const int tid = threadIdx.x;
  const int w = tid >> 6;
  const int lane = tid & 63;
  const int g = lane >> 4, c = lane & 15;
  const int MT0 = blockIdx.x << 2;
  const int yh = (STAGE == 1) ? blockIdx.y : 0;
  const int KC = (STAGE == 2) ? 16 : 8;
  const int AKC = (STAGE == 2) ? 16 : 8;

  f32x4 acc[4][4];
#pragma unroll
  for (int i = 0; i < 4; ++i)
#pragma unroll
    for (int j = 0; j < 4; ++j) acc[i][j] = (f32x4){0.f, 0.f, 0.f, 0.f};

  const unsigned short* bbase = Bg + ((STAGE == 1) ? (size_t)yh * 8192 : 0);
  const size_t bstride = (STAGE == 1) ? 16384 : 8192;

  for (int kc = 0; kc < KC; ++kc) {
    bf16x8 af[4];
#pragma unroll
    for (int mt = 0; mt < 4; ++mt)
      af[mt] = *(const bf16x8*)(Ag + ((size_t)(MT0 + mt) * AKC + kc) * 512 + lane * 8);
    __syncthreads();
    const unsigned short* src = bbase + (size_t)kc * bstride;
#pragma unroll
    for (int p = 0; p < 4; ++p) {
      int idx = tid + 256 * p;
      *(uint4*)&smemB[idx * 8] = *(const uint4*)&src[idx * 8];
    }
    __syncthreads();
#pragma unroll
    for (int nt = 0; nt < 4; ++nt) {
      bf16x8 bfv = *(const bf16x8*)&smemB[(w * 4 + nt) * 512 + lane * 8];
#pragma unroll
      for (int mt = 0; mt < 4; ++mt)
        acc[mt][nt] = __builtin_amdgcn_mfma_f32_16x16x32_bf16(af[mt], bfv, acc[mt][nt], 0, 0, 0);
    }
  }

  if (STAGE == 0) {
    float pg[4], pb[4];
#pragma unroll
    for (int nt = 0; nt < 4; ++nt) {
      int col = w * 64 + nt * 16 + c;
      pg[nt] = lng[col]; pb[nt] = lnb[col];
    }
#pragma unroll
    for (int mt = 0; mt < 4; ++mt)
#pragma unroll
      for (int r = 0; r < 4; ++r) {
        float s1 = 0.f, s2 = 0.f;
#pragma unroll
        for (int nt = 0; nt < 4; ++nt) { float v = acc[mt][nt][r]; s1 += v; s2 += v * v; }
#pragma unroll
        for (int m = 1; m < 16; m <<= 1) { s1 += __shfl_xor(s1, m, 64); s2 += __shfl_xor(s2, m, 64); }
        if (c == 0) {
          ps1[w * 64 + mt * 16 + g * 4 + r] = s1;
          ps2[w * 64 + mt * 16 + g * 4 + r] = s2;
        }
      }
    __syncthreads();
#pragma unroll
    for (int mt = 0; mt < 4; ++mt)
#pragma unroll
      for (int r = 0; r < 4; ++r) {
        int row = mt * 16 + g * 4 + r;
        float s1 = ps1[row] + ps1[64 + row] + ps1[128 + row] + ps1[192 + row];
        float s2 = ps2[row] + ps2[64 + row] + ps2[128 + row] + ps2[192 + row];
        float mu = s1 * (1.f / 256.f);
        float var = s2 * (1.f / 256.f) - mu * mu;
        float inv = 1.f / sqrtf(var + 1e-6f);
#pragma unroll
        for (int nt = 0; nt < 4; ++nt) {
          float v = (acc[mt][nt][r] - mu) * inv * pg[nt] + pb[nt];
          swz[row * 264 + w * 64 + nt * 16 + c] = f2bf(v);
        }
      }
    __syncthreads();
#pragma unroll
    for (int i = 0; i < 8; ++i) {
      int f = tid + 256 * i;
      int mtl = f >> 9, kcl = (f >> 6) & 7, L = f & 63;
      int row = mtl * 16 + (L & 15), k0 = kcl * 32 + (L >> 4) * 8;
      uint4 v = *(const uint4*)&swz[row * 264 + k0];
      *(uint4*)&Og[(((size_t)(MT0 + mtl) * 8 + kcl) << 9) + L * 8] = v;
    }
  }

  if (STAGE == 1) {
#pragma unroll
    for (int mt = 0; mt < 4; ++mt)
#pragma unroll
      for (int r = 0; r < 4; ++r) {
        int row = mt * 16 + g * 4 + r;
#pragma unroll
        for (int nt = 0; nt < 4; ++nt)
          swz[row * 264 + w * 64 + nt * 16 + c] = f2bf(fmaxf(acc[mt][nt][r], 0.f));
      }
    __syncthreads();
#pragma unroll
    for (int i = 0; i < 8; ++i) {
      int f = tid + 256 * i;
      int mtl = f >> 9, kcl = (f >> 6) & 7, L = f & 63;
      int row = mtl * 16 + (L & 15), k0 = kcl * 32 + (L >> 4) * 8;
      uint4 v = *(const uint4*)&swz[row * 264 + k0];
      *(uint4*)&Og[(((size_t)(MT0 + mtl) * 16 + yh * 8 + kcl) << 9) + L * 8] = v;
    }
  }

  if (STAGE == 2) {
    float pg[4], pb[4];
#pragma unroll
    for (int nt = 0; nt < 4; ++nt) {
      int col = w * 64 + nt * 16 + c;
      pg[nt] = lng[col]; pb[nt] = lnb[col];
    }
    // sigmoid in place
#pragma unroll
    for (int mt = 0; mt < 4; ++mt)
#pragma unroll
      for (int nt = 0; nt < 4; ++nt)
#pragma unroll
        for (int r = 0; r < 4; ++r)
          acc[mt][nt][r] = 1.f / (1.f + expf(-acc[mt][nt][r]));
#pragma unroll
    for (int mt = 0; mt < 4; ++mt)
#pragma unroll
      for (int r = 0; r < 4; ++r) {
        float s1 = 0.f, s2 = 0.f;
#pragma unroll
        for (int nt = 0; nt < 4; ++nt) { float v = acc[mt][nt][r]; s1 += v; s2 += v * v; }
#pragma unroll
        for (int m = 1; m < 16; m <<= 1) { s1 += __shfl_xor(s1, m, 64); s2 += __shfl_xor(s2, m, 64); }
        if (c == 0) {
          ps1[w * 64 + mt * 16 + g * 4 + r] = s1;
          ps2[w * 64 + mt * 16 + g * 4 + r] = s2;
        }
      }
    __syncthreads();
    float mu_[4][4], inv_[4][4];
#pragma unroll
    for (int mt = 0; mt < 4; ++mt)
#pragma unroll
      for (int r = 0; r < 4; ++r) {
        int row = mt * 16 + g * 4 + r;
        float s1 = ps1[row] + ps1[64 + row] + ps1[128 + row] + ps1[192 + row];
        float s2 = ps2[row] + ps2[64 + row] + ps2[128 + row] + ps2[192 + row];
        float mu = s1 * (1.f / 256.f);
        float var = s2 * (1.f / 256.f) - mu * mu;
        mu_[mt][r] = mu;
        inv_[mt][r] = 1.f / sqrtf(var + 1e-6f);
      }
    // fw -> LDS transposed [col][68 rows], packed 4 rows per write
#pragma unroll
    for (int mt = 0; mt < 4; ++mt)
#pragma unroll
      for (int nt = 0; nt < 4; ++nt) {
        alignas(8) unsigned short tmp[4];
#pragma unroll
        for (int r = 0; r < 4; ++r)
          tmp[r] = f2bf((acc[mt][nt][r] - mu_[mt][r]) * inv_[mt][r] * pg[nt] + pb[nt]);
        int col = w * 64 + nt * 16 + c;
        *(uint2*)&swz[col * 68 + mt * 16 + g * 4] = *(const uint2*)tmp;
      }
    __syncthreads();
    const int row0 = MT0 << 4;
    const int b = row0 >> 12;
    const int l0 = row0 & 4095;
    const int li = tid & 63, cq = tid >> 6;
    for (int i = 0; i < 64; ++i) {
      int ccol = cq * 64 + i;
      float fwv = bf2f(swz[ccol * 68 + li]);
      size_t xoff = (((size_t)(MT0 + (li >> 4)) * 8 + (ccol >> 5)) << 9) +
                    (((((ccol >> 3) & 3) << 4) + (li & 15)) << 3) + (ccol & 7);
      float xpv = bf2f(xpsw[xoff]);
      size_t o = ((size_t)((b << 8) + ccol)) * LL + l0 + li;
      float ov = fmaf(xpv, fwv, xin[o]);
      outp[o] = fmaxf(ov, 0.f);
    }
  }
}

extern "C" void kernel_launch(void* const* d_in, const int* in_sizes, int n_in,
                              void* d_out, int out_size, void* d_ws, size_t ws_size,
                              hipStream_t stream) {
  const float* x    = (const float*)d_in[0];
  const float* w1   = (const float*)d_in[1];
  const float* g1   = (const float*)d_in[2];
  const float* b1   = (const float*)d_in[3];
  const float* m1   = (const float*)d_in[4];
  const float* v1   = (const float*)d_in[5];
  const float* w2   = (const float*)d_in[6];
  const float* g2   = (const float*)d_in[7];
  const float* b2   = (const float*)d_in[8];
  const float* m2   = (const float*)d_in[9];
  const float* v2   = (const float*)d_in[10];
  const float* fc1  = (const float*)d_in[11];
  const float* fc2  = (const float*)d_in[12];
  const float* lng  = (const float*)d_in[13];
  const float* lnb  = (const float*)d_in[14];
  float* out = (float*)d_out;

  float* ws = (float*)d_ws;
  float* w1f = ws;                                   // 196608
  float* w2f = ws + 196608;                          // 196608
  float* b1f = ws + 393216;                          // 256
  float* b2f = ws + 393472;                          // 256
  unsigned short* Bd = (unsigned short*)(ws + 393728);   // 65536 bf16 (32768 fl)
  unsigned short* B1 = (unsigned short*)(ws + 426496);   // 131072 bf16 (65536 fl)
  unsigned short* B2 = (unsigned short*)(ws + 492032);   // 131072 bf16 (65536 fl)
  float* out1 = ws + 557568;                         // 33554432 fl (conv1 out; later aliased by h_sw)
  unsigned short* h_sw = (unsigned short*)out1;      // 67108864 bf16 = 33554432 fl (alias, safe: out1 dead)
  unsigned short* xp_sw = (unsigned short*)(ws + 34112000); // 33554432 bf16 (16777216 fl)
  unsigned short* sd_sw = (unsigned short*)(ws + 50889216); // 33554432 bf16 (16777216 fl)
  // total 67666432 floats = 270.7 MB

  init_fold<<<768, 256, 0, stream>>>(w1, g1, b1, m1, v1, w2, g2, b2, m2, v2,
                                     w1f, b1f, w2f, b2f);
  init_bsw<<<1280, 256, 0, stream>>>(fc1, fc2, Bd, B1, B2);

  dim3 cgrid(LL / 128, CC / 32, BB);
  conv_bn_kernel<true, false><<<cgrid, 256, 0, stream>>>(x, w1f, b1f, out1, nullptr);
  conv_bn_kernel<false, true><<<cgrid, 256, 0, stream>>>(out1, w2f, b2f, nullptr, xp_sw);

  gemm_stage<0><<<2048, 256, 0, stream>>>(xp_sw, Bd, lng, lnb, sd_sw, nullptr, nullptr, nullptr);
  gemm_stage<1><<<dim3(2048, 2), 256, 0, stream>>>(sd_sw, B1, nullptr, nullptr, h_sw,
                                                   nullptr, nullptr, nullptr);
  gemm_stage<2><<<2048, 256, 0, stream>>>(h_sw, B2, lng, lnb, nullptr, xp_sw, x, out);
}

// Round 4
// 652.104 us; speedup vs baseline: 11.2343x; 3.9238x over previous
//
#include <hip/hip_runtime.h>
#include <math.h>

#define BB 32
#define CC 256
#define LL 4096

typedef __attribute__((ext_vector_type(8))) short bf16x8;
typedef __attribute__((ext_vector_type(4))) float f32x4;

__device__ __forceinline__ unsigned short f2bf(float f) {
  unsigned u = __float_as_uint(f);
  u = (u + 0x7FFFu + ((u >> 16) & 1u)) >> 16;
  return (unsigned short)u;
}
__device__ __forceinline__ float bf2f(unsigned short v) {
  return __uint_as_float(((unsigned)v) << 16);
}

// ---------------- init: biases (BN folded) ----------------
__global__ void init_bias(const float* __restrict__ g1, const float* __restrict__ b1,
                          const float* __restrict__ m1, const float* __restrict__ v1,
                          const float* __restrict__ g2, const float* __restrict__ b2,
                          const float* __restrict__ m2, const float* __restrict__ v2,
                          float* __restrict__ b1f, float* __restrict__ b2f) {
  int c = threadIdx.x;
  b1f[c] = b1[c] - m1[c] * g1[c] * rsqrtf(v1[c] + 1e-5f);
  b2f[c] = b2[c] - m2[c] * g2[c] * rsqrtf(v2[c] + 1e-5f);
}

// ---------------- init: conv weights, B-frag-linear bf16, BN-folded ----------------
// chunk (kc*3+t): [nt 16][L 64][j 8]; element = w[co=nt*16+(L&15)][ci=kc*32+(L>>4)*8+j][t]*s(co)
__global__ void init_wsw(const float* __restrict__ w1, const float* __restrict__ g1,
                         const float* __restrict__ v1,
                         const float* __restrict__ w2, const float* __restrict__ g2,
                         const float* __restrict__ v2,
                         unsigned short* __restrict__ W1sw, unsigned short* __restrict__ W2sw) {
  int id = blockIdx.x * 256 + threadIdx.x; // 393216
  int cv = id / 196608;
  int i = id - cv * 196608;
  int kc3t = i >> 13;
  int kc = kc3t / 3, t = kc3t - 3 * kc;
  int rem = i & 8191;
  int nt = rem >> 9, L = (rem >> 3) & 63, j = i & 7;
  int co = nt * 16 + (L & 15);
  int ci = kc * 32 + ((L >> 4) << 3) + j;
  if (cv == 0) {
    float s = g1[co] * rsqrtf(v1[co] + 1e-5f);
    W1sw[i] = f2bf(w1[(co * 256 + ci) * 3 + t] * s);
  } else {
    float s = g2[co] * rsqrtf(v2[co] + 1e-5f);
    W2sw[i] = f2bf(w2[(co * 256 + ci) * 3 + t] * s);
  }
}

// ---------------- init: GEMM-chain B matrices, frag-linear bf16 ----------------
__global__ void init_bsw(const float* __restrict__ fc1, const float* __restrict__ fc2,
                         unsigned short* __restrict__ Bd, unsigned short* __restrict__ B1,
                         unsigned short* __restrict__ B2) {
  int id = blockIdx.x * 256 + threadIdx.x; // 327680 total
  if (id < 65536) {
    int i = id;
    int kc = i >> 13, nt = (i >> 9) & 15, L = (i >> 3) & 63, j = i & 7;
    int n = nt * 16 + (L & 15), k = kc * 32 + (L >> 4) * 8 + j;
    double v = 2.0 * cos(3.14159265358979323846 * (double)n * (2.0 * k + 1.0) / 512.0);
    Bd[i] = f2bf((float)v);
  } else if (id < 65536 + 131072) {
    int i = id - 65536;
    int kc = i >> 14, nt = (i >> 9) & 31, L = (i >> 3) & 63, j = i & 7;
    int n = nt * 16 + (L & 15), k = kc * 32 + (L >> 4) * 8 + j;
    B1[i] = f2bf(fc1[n * 256 + k]);
  } else {
    int i = id - 65536 - 131072;
    int kc = i >> 13, nt = (i >> 9) & 15, L = (i >> 3) & 63, j = i & 7;
    int n = nt * 16 + (L & 15), k = kc * 32 + (L >> 4) * 8 + j;
    B2[i] = f2bf(fc2[n * 512 + k]);
  }
}

// ---------------- transpose: x fp32 [b][ci][l] -> xT bf16 [b][l][ci] ----------------
__global__ __launch_bounds__(256) void transpose_x(const float* __restrict__ x,
                                                   unsigned short* __restrict__ xT) {
  __shared__ unsigned short ts[64][68];
  const int tid = threadIdx.x;
  const int b = blockIdx.z, ci0 = blockIdx.y << 6, l0 = blockIdx.x << 6;
#pragma unroll
  for (int p = 0; p < 4; ++p) {
    int cc = (p << 4) + (tid >> 4);
    int ll = (tid & 15) << 2;
    float4 v = *(const float4*)&x[((((size_t)b << 8) + ci0 + cc) << 12) + l0 + ll];
    ts[ll + 0][cc] = f2bf(v.x);
    ts[ll + 1][cc] = f2bf(v.y);
    ts[ll + 2][cc] = f2bf(v.z);
    ts[ll + 3][cc] = f2bf(v.w);
  }
  __syncthreads();
#pragma unroll
  for (int p = 0; p < 4; ++p) {
    int idx = tid + (p << 8);
    int row = idx >> 4, ch = idx & 15;
    uint2 v = *(const uint2*)&ts[row][ch << 2];
    *(uint2*)&xT[((((size_t)b << 12) + l0 + row) << 8) + ci0 + (ch << 2)] = v;
  }
}

// ---------------- conv as implicit GEMM (MFMA bf16 16x16x32) ----------------
// block: 64 l x 256 co, one b. K = (8 ci-chunks) x (3 taps).
// FRAGOUT=false: out bf16 [b][l][co] rows (+bias, RELU). FRAGOUT=true: A-frag-linear (+bias).
template <bool RELU, bool FRAGOUT>
__global__ __launch_bounds__(256, 3) void conv_mfma(
    const unsigned short* __restrict__ inT, const unsigned short* __restrict__ Wsw,
    const float* __restrict__ bias, unsigned short* __restrict__ outT) {
  __shared__ char smem[51232];
  unsigned short* xs = (unsigned short*)smem;              // [66][264]
  unsigned short* smemB = (unsigned short*)(smem + 34848); // 16 KB chunk (8192 shorts)
  unsigned short* swz = (unsigned short*)smem;             // epilogue alias [64][264]

  const int tid = threadIdx.x;
  const int w = tid >> 6, lane = tid & 63;
  const int g = lane >> 4, c = lane & 15;
  const int l0 = blockIdx.x << 6;
  const int b = blockIdx.y;
  const size_t rowbase = ((size_t)b << 12) + l0;

  // stage xs: rows l0-1 .. l0+64 (66), 256 ci each
  for (int idx = tid; idx < 66 * 32; idx += 256) {
    int r = idx >> 5, ch = idx & 31;
    int gl = l0 - 1 + r;
    uint4 v = {0, 0, 0, 0};
    if (gl >= 0 && gl < LL)
      v = *(const uint4*)&inT[((((size_t)b << 12) + gl) << 8) + (ch << 3)];
    *(uint4*)&xs[r * 264 + (ch << 3)] = v;
  }

  f32x4 acc[4][4];
#pragma unroll
  for (int i = 0; i < 4; ++i)
#pragma unroll
    for (int j = 0; j < 4; ++j) acc[i][j] = (f32x4){0.f, 0.f, 0.f, 0.f};

  for (int kc = 0; kc < 8; ++kc)
#pragma unroll
    for (int t = 0; t < 3; ++t) {
      __syncthreads();
      const unsigned short* src = Wsw + ((kc * 3 + t) << 13);
#pragma unroll
      for (int p = 0; p < 4; ++p) {
        int idx = tid + (p << 8);
        *(uint4*)&smemB[idx << 3] = *(const uint4*)&src[idx << 3];
      }
      __syncthreads();
      bf16x8 af[4];
#pragma unroll
      for (int mt = 0; mt < 4; ++mt)
        af[mt] = *(const bf16x8*)&xs[(mt * 16 + c + t) * 264 + (kc << 5) + (g << 3)];
#pragma unroll
      for (int nt = 0; nt < 4; ++nt) {
        bf16x8 bfv = *(const bf16x8*)&smemB[((w << 2) + nt) * 512 + (lane << 3)];
#pragma unroll
        for (int mt = 0; mt < 4; ++mt)
          acc[mt][nt] = __builtin_amdgcn_mfma_f32_16x16x32_bf16(af[mt], bfv, acc[mt][nt], 0, 0, 0);
      }
    }
  __syncthreads();

  float pb[4];
#pragma unroll
  for (int nt = 0; nt < 4; ++nt) pb[nt] = bias[(w << 6) + nt * 16 + c];
#pragma unroll
  for (int mt = 0; mt < 4; ++mt)
#pragma unroll
    for (int r = 0; r < 4; ++r) {
      int row = mt * 16 + g * 4 + r;
#pragma unroll
      for (int nt = 0; nt < 4; ++nt) {
        float v = acc[mt][nt][r] + pb[nt];
        if (RELU) v = fmaxf(v, 0.f);
        swz[row * 264 + (w << 6) + nt * 16 + c] = f2bf(v);
      }
    }
  __syncthreads();
  if (!FRAGOUT) {
#pragma unroll
    for (int i = 0; i < 8; ++i) {
      int idx = tid + (i << 8);
      int row = idx >> 5, ch = idx & 31;
      *(uint4*)&outT[((rowbase + row) << 8) + (ch << 3)] = *(const uint4*)&swz[row * 264 + (ch << 3)];
    }
  } else {
    const int MT0 = (int)(rowbase >> 4);
#pragma unroll
    for (int i = 0; i < 8; ++i) {
      int f = tid + (i << 8);
      int mtl = f >> 9, kcl = (f >> 6) & 7, L = f & 63;
      int row = mtl * 16 + (L & 15), k0 = (kcl << 5) + ((L >> 4) << 3);
      uint4 v = *(const uint4*)&swz[row * 264 + k0];
      *(uint4*)&outT[(((size_t)(MT0 + mtl) * 8 + kcl) << 9) + L * 8] = v;
    }
  }
}

// ---------------- fused GEMM chain (MFMA 16x16x32 bf16) ----------------
template <int STAGE>
__global__ __launch_bounds__(256, 3) void gemm_stage(
    const unsigned short* __restrict__ Ag, const unsigned short* __restrict__ Bg,
    const float* __restrict__ lng, const float* __restrict__ lnb,
    unsigned short* __restrict__ Og,
    const unsigned short* __restrict__ xpsw, const float* __restrict__ xin,
    float* __restrict__ outp) {
  __shared__ char smem[53248];
  unsigned short* smemB = (unsigned short*)smem;
  unsigned short* swz = (unsigned short*)(smem + 16384);
  float* ps1 = (float*)(smem + 51200);
  float* ps2 = (float*)(smem + 51200 + 1024);

  const int tid = threadIdx.x;
  const int w = tid >> 6;
  const int lane = tid & 63;
  const int g = lane >> 4, c = lane & 15;
  const int MT0 = blockIdx.x << 2;
  const int yh = (STAGE == 1) ? blockIdx.y : 0;
  const int KC = (STAGE == 2) ? 16 : 8;
  const int AKC = (STAGE == 2) ? 16 : 8;

  f32x4 acc[4][4];
#pragma unroll
  for (int i = 0; i < 4; ++i)
#pragma unroll
    for (int j = 0; j < 4; ++j) acc[i][j] = (f32x4){0.f, 0.f, 0.f, 0.f};

  const unsigned short* bbase = Bg + ((STAGE == 1) ? (size_t)yh * 8192 : 0);
  const size_t bstride = (STAGE == 1) ? 16384 : 8192;

  for (int kc = 0; kc < KC; ++kc) {
    bf16x8 af[4];
#pragma unroll
    for (int mt = 0; mt < 4; ++mt)
      af[mt] = *(const bf16x8*)(Ag + ((size_t)(MT0 + mt) * AKC + kc) * 512 + lane * 8);
    __syncthreads();
    const unsigned short* src = bbase + (size_t)kc * bstride;
#pragma unroll
    for (int p = 0; p < 4; ++p) {
      int idx = tid + 256 * p;
      *(uint4*)&smemB[idx * 8] = *(const uint4*)&src[idx * 8];
    }
    __syncthreads();
#pragma unroll
    for (int nt = 0; nt < 4; ++nt) {
      bf16x8 bfv = *(const bf16x8*)&smemB[(w * 4 + nt) * 512 + lane * 8];
#pragma unroll
      for (int mt = 0; mt < 4; ++mt)
        acc[mt][nt] = __builtin_amdgcn_mfma_f32_16x16x32_bf16(af[mt], bfv, acc[mt][nt], 0, 0, 0);
    }
  }

  if (STAGE == 0) {
    float pg[4], pb[4];
#pragma unroll
    for (int nt = 0; nt < 4; ++nt) {
      int col = w * 64 + nt * 16 + c;
      pg[nt] = lng[col]; pb[nt] = lnb[col];
    }
#pragma unroll
    for (int mt = 0; mt < 4; ++mt)
#pragma unroll
      for (int r = 0; r < 4; ++r) {
        float s1 = 0.f, s2 = 0.f;
#pragma unroll
        for (int nt = 0; nt < 4; ++nt) { float v = acc[mt][nt][r]; s1 += v; s2 += v * v; }
#pragma unroll
        for (int m = 1; m < 16; m <<= 1) { s1 += __shfl_xor(s1, m, 64); s2 += __shfl_xor(s2, m, 64); }
        if (c == 0) {
          ps1[w * 64 + mt * 16 + g * 4 + r] = s1;
          ps2[w * 64 + mt * 16 + g * 4 + r] = s2;
        }
      }
    __syncthreads();
#pragma unroll
    for (int mt = 0; mt < 4; ++mt)
#pragma unroll
      for (int r = 0; r < 4; ++r) {
        int row = mt * 16 + g * 4 + r;
        float s1 = ps1[row] + ps1[64 + row] + ps1[128 + row] + ps1[192 + row];
        float s2 = ps2[row] + ps2[64 + row] + ps2[128 + row] + ps2[192 + row];
        float mu = s1 * (1.f / 256.f);
        float var = s2 * (1.f / 256.f) - mu * mu;
        float inv = 1.f / sqrtf(var + 1e-6f);
#pragma unroll
        for (int nt = 0; nt < 4; ++nt) {
          float v = (acc[mt][nt][r] - mu) * inv * pg[nt] + pb[nt];
          swz[row * 264 + w * 64 + nt * 16 + c] = f2bf(v);
        }
      }
    __syncthreads();
#pragma unroll
    for (int i = 0; i < 8; ++i) {
      int f = tid + 256 * i;
      int mtl = f >> 9, kcl = (f >> 6) & 7, L = f & 63;
      int row = mtl * 16 + (L & 15), k0 = kcl * 32 + (L >> 4) * 8;
      uint4 v = *(const uint4*)&swz[row * 264 + k0];
      *(uint4*)&Og[(((size_t)(MT0 + mtl) * 8 + kcl) << 9) + L * 8] = v;
    }
  }

  if (STAGE == 1) {
#pragma unroll
    for (int mt = 0; mt < 4; ++mt)
#pragma unroll
      for (int r = 0; r < 4; ++r) {
        int row = mt * 16 + g * 4 + r;
#pragma unroll
        for (int nt = 0; nt < 4; ++nt)
          swz[row * 264 + w * 64 + nt * 16 + c] = f2bf(fmaxf(acc[mt][nt][r], 0.f));
      }
    __syncthreads();
#pragma unroll
    for (int i = 0; i < 8; ++i) {
      int f = tid + 256 * i;
      int mtl = f >> 9, kcl = (f >> 6) & 7, L = f & 63;
      int row = mtl * 16 + (L & 15), k0 = kcl * 32 + (L >> 4) * 8;
      uint4 v = *(const uint4*)&swz[row * 264 + k0];
      *(uint4*)&Og[(((size_t)(MT0 + mtl) * 16 + yh * 8 + kcl) << 9) + L * 8] = v;
    }
  }

  if (STAGE == 2) {
    float pg[4], pb[4];
#pragma unroll
    for (int nt = 0; nt < 4; ++nt) {
      int col = w * 64 + nt * 16 + c;
      pg[nt] = lng[col]; pb[nt] = lnb[col];
    }
#pragma unroll
    for (int mt = 0; mt < 4; ++mt)
#pragma unroll
      for (int nt = 0; nt < 4; ++nt)
#pragma unroll
        for (int r = 0; r < 4; ++r)
          acc[mt][nt][r] = 1.f / (1.f + expf(-acc[mt][nt][r]));
#pragma unroll
    for (int mt = 0; mt < 4; ++mt)
#pragma unroll
      for (int r = 0; r < 4; ++r) {
        float s1 = 0.f, s2 = 0.f;
#pragma unroll
        for (int nt = 0; nt < 4; ++nt) { float v = acc[mt][nt][r]; s1 += v; s2 += v * v; }
#pragma unroll
        for (int m = 1; m < 16; m <<= 1) { s1 += __shfl_xor(s1, m, 64); s2 += __shfl_xor(s2, m, 64); }
        if (c == 0) {
          ps1[w * 64 + mt * 16 + g * 4 + r] = s1;
          ps2[w * 64 + mt * 16 + g * 4 + r] = s2;
        }
      }
    __syncthreads();
    float mu_[4][4], inv_[4][4];
#pragma unroll
    for (int mt = 0; mt < 4; ++mt)
#pragma unroll
      for (int r = 0; r < 4; ++r) {
        int row = mt * 16 + g * 4 + r;
        float s1 = ps1[row] + ps1[64 + row] + ps1[128 + row] + ps1[192 + row];
        float s2 = ps2[row] + ps2[64 + row] + ps2[128 + row] + ps2[192 + row];
        float mu = s1 * (1.f / 256.f);
        float var = s2 * (1.f / 256.f) - mu * mu;
        mu_[mt][r] = mu;
        inv_[mt][r] = 1.f / sqrtf(var + 1e-6f);
      }
#pragma unroll
    for (int mt = 0; mt < 4; ++mt)
#pragma unroll
      for (int nt = 0; nt < 4; ++nt) {
        alignas(8) unsigned short tmp[4];
#pragma unroll
        for (int r = 0; r < 4; ++r)
          tmp[r] = f2bf((acc[mt][nt][r] - mu_[mt][r]) * inv_[mt][r] * pg[nt] + pb[nt]);
        int col = w * 64 + nt * 16 + c;
        *(uint2*)&swz[col * 68 + mt * 16 + g * 4] = *(const uint2*)tmp;
      }
    __syncthreads();
    const int row0 = MT0 << 4;
    const int b = row0 >> 12;
    const int l0 = row0 & 4095;
    const int li = tid & 63, cq = tid >> 6;
    for (int i = 0; i < 64; ++i) {
      int ccol = cq * 64 + i;
      float fwv = bf2f(swz[ccol * 68 + li]);
      size_t xoff = (((size_t)(MT0 + (li >> 4)) * 8 + (ccol >> 5)) << 9) +
                    (((((ccol >> 3) & 3) << 4) + (li & 15)) << 3) + (ccol & 7);
      float xpv = bf2f(xpsw[xoff]);
      size_t o = ((size_t)((b << 8) + ccol)) * LL + l0 + li;
      float ov = fmaf(xpv, fwv, xin[o]);
      outp[o] = fmaxf(ov, 0.f);
    }
  }
}

extern "C" void kernel_launch(void* const* d_in, const int* in_sizes, int n_in,
                              void* d_out, int out_size, void* d_ws, size_t ws_size,
                              hipStream_t stream) {
  const float* x    = (const float*)d_in[0];
  const float* w1   = (const float*)d_in[1];
  const float* g1   = (const float*)d_in[2];
  const float* b1   = (const float*)d_in[3];
  const float* m1   = (const float*)d_in[4];
  const float* v1   = (const float*)d_in[5];
  const float* w2   = (const float*)d_in[6];
  const float* g2   = (const float*)d_in[7];
  const float* b2   = (const float*)d_in[8];
  const float* m2   = (const float*)d_in[9];
  const float* v2   = (const float*)d_in[10];
  const float* fc1  = (const float*)d_in[11];
  const float* fc2  = (const float*)d_in[12];
  const float* lng  = (const float*)d_in[13];
  const float* lnb  = (const float*)d_in[14];
  float* out = (float*)d_out;

  float* ws = (float*)d_ws;
  float* b1f = ws;                                        // 256
  float* b2f = ws + 256;                                  // 256
  unsigned short* Bd   = (unsigned short*)(ws + 512);     // 65536 bf16
  unsigned short* B1   = (unsigned short*)(ws + 33280);   // 131072 bf16
  unsigned short* B2   = (unsigned short*)(ws + 98816);   // 131072 bf16
  unsigned short* W1sw = (unsigned short*)(ws + 164352);  // 196608 bf16
  unsigned short* W2sw = (unsigned short*)(ws + 262656);  // 196608 bf16
  // regionA: xT (dead after conv1) -> sd_sw
  unsigned short* xT    = (unsigned short*)(ws + 360960);    // 33554432 bf16
  unsigned short* sd_sw = xT;
  // regionB: y1T (dead after conv2) -> h_sw (h spans y1T + the following gap)
  unsigned short* y1T  = (unsigned short*)(ws + 17138176);   // 33554432 bf16
  unsigned short* h_sw = y1T;                                // 67108864 bf16
  // regionC: xp_sw (live to the end)
  unsigned short* xp_sw = (unsigned short*)(ws + 50692608);  // 33554432 bf16
  // total 67469824 floats = 269.9 MB

  init_bias<<<1, 256, 0, stream>>>(g1, b1, m1, v1, g2, b2, m2, v2, b1f, b2f);
  init_wsw<<<1536, 256, 0, stream>>>(w1, g1, v1, w2, g2, v2, W1sw, W2sw);
  init_bsw<<<1280, 256, 0, stream>>>(fc1, fc2, Bd, B1, B2);

  transpose_x<<<dim3(64, 4, 32), 256, 0, stream>>>(x, xT);

  conv_mfma<true, false><<<dim3(64, 32), 256, 0, stream>>>(xT, W1sw, b1f, y1T);
  conv_mfma<false, true><<<dim3(64, 32), 256, 0, stream>>>(y1T, W2sw, b2f, xp_sw);

  gemm_stage<0><<<2048, 256, 0, stream>>>(xp_sw, Bd, lng, lnb, sd_sw, nullptr, nullptr, nullptr);
  gemm_stage<1><<<dim3(2048, 2), 256, 0, stream>>>(sd_sw, B1, nullptr, nullptr, h_sw,
                                                   nullptr, nullptr, nullptr);
  gemm_stage<2><<<2048, 256, 0, stream>>>(h_sw, B2, lng, lnb, nullptr, xp_sw, x, out);
}